// Round 11
// baseline (292.790 us; speedup 1.0000x reference)
//
#include <hip/hip_runtime.h>
#include <hip/hip_bf16.h>

typedef unsigned short u16;
typedef unsigned int u32;
typedef float f32x4 __attribute__((ext_vector_type(4)));
typedef u16 u16x4 __attribute__((ext_vector_type(4)));
typedef u16 u16x8 __attribute__((ext_vector_type(8)));
typedef __bf16 bf16x8 __attribute__((ext_vector_type(8)));

#define OUT_DIM 4096
#define IN_DIM  4096
#define M_DIM   8192   // 4 * 2048

__device__ __forceinline__ u16 f2bf(float f) {
  u32 u = __builtin_bit_cast(u32, f);
  return (u16)((u + 0x7FFFu + ((u >> 16) & 1u)) >> 16);
}

// ---------------------------------------------------------------------------
// W build: codebook gather + sign unpack + 2-level inverse Haar + scale -> bf16
// ---------------------------------------------------------------------------
__global__ __launch_bounds__(256) void build_w_kernel(
    const float* __restrict__ codebook, const float* __restrict__ scales,
    const int* __restrict__ indices, const int* __restrict__ signs,
    u16* __restrict__ W) {
  __shared__ float c[IN_DIM];
  const int o   = blockIdx.x;
  const int tid = threadIdx.x;
  for (int g = tid; g < IN_DIM / 8; g += 256) {
    const int idx = indices[o * (IN_DIM / 8) + g];
    const int sp  = signs[o * (IN_DIM / 8) + g];
    f32x4 c0 = *(const f32x4*)&codebook[idx * 8];
    f32x4 c1 = *(const f32x4*)&codebook[idx * 8 + 4];
    float v[8] = {c0[0], c0[1], c0[2], c0[3], c1[0], c1[1], c1[2], c1[3]};
#pragma unroll
    for (int j = 0; j < 8; ++j)
      c[g * 8 + j] = ((sp >> j) & 1) ? v[j] : -v[j];
  }
  __syncthreads();
  const float scale = scales[o];
  const float S = 0.70710678118654752440f;
  for (int t = tid; t < IN_DIM / 4; t += 256) {
    float a   = c[t];
    float d1  = c[IN_DIM / 4 + t];
    float d2a = c[IN_DIM / 2 + 2 * t];
    float d2b = c[IN_DIM / 2 + 2 * t + 1];
    float e  = (a + d1) * S;
    float od = (a - d1) * S;
    u16x4 w;
    w[0] = f2bf((e  + d2a) * S * scale);
    w[1] = f2bf((e  - d2a) * S * scale);
    w[2] = f2bf((od + d2b) * S * scale);
    w[3] = f2bf((od - d2b) * S * scale);
    *(u16x4*)&W[(size_t)o * IN_DIM + 4 * t] = w;
  }
}

// ---------------------------------------------------------------------------
// X f32 -> bf16
// ---------------------------------------------------------------------------
__global__ __launch_bounds__(256) void cvt_x_kernel(
    const float* __restrict__ X, u16* __restrict__ Xb) {
  const int stride = gridDim.x * blockDim.x;
  const int n8 = (M_DIM * IN_DIM) / 8;
  for (int i = blockIdx.x * blockDim.x + threadIdx.x; i < n8; i += stride) {
    f32x4 a = *(const f32x4*)&X[(size_t)i * 8];
    f32x4 b = *(const f32x4*)&X[(size_t)i * 8 + 4];
    u16x8 r;
    r[0] = f2bf(a[0]); r[1] = f2bf(a[1]); r[2] = f2bf(a[2]); r[3] = f2bf(a[3]);
    r[4] = f2bf(b[0]); r[5] = f2bf(b[1]); r[6] = f2bf(b[2]); r[7] = f2bf(b[3]);
    *(u16x8*)&Xb[(size_t)i * 8] = r;
  }
}

// ---------------------------------------------------------------------------
// GEMM: C[M][N] f32 = A[M][K](bf16) x B[N][K](bf16, B^T layout).
// R11 = R10 + read-ahead-by-one: phase p issues the ds_reads feeding phase
// p+1 (ping-pong regs aq0/aq1, bq0/bq1), so the ~440cy/CU LDS drain runs
// UNDER phase p's ~621cy MFMA cluster; the pre-MFMA wall is a COUNTED
// lgkmcnt (leaves this phase's reads in flight). One sched_barrier(0)
// before s_barrier pins [reads][stage][gate] pre-barrier; the MFMA region
// stays compiler-scheduled (R7's dual-wall mistake avoided).
// Hazards (re-derived, all formal):
//  RAW: gates VM4 AFTER the stage at even phases; each region retired
//   exactly 2 phases + 1 barrier before its read-issue (prologue VM4
//   covers iter-0 p2). Youngest gate-waited load 2 phases (~1400cy) old.
//  WAR: stage@q has region's last read-issue @q-3; that read completes at
//   the counted wall@q-2, which precedes that wave's arrival at
//   barrier(q-1), which precedes any wave's stage@q.
//  Regs: write/read sets disjoint every phase (verified p1..p8).
// Unchanged: 16x16x32 MFMA, BM=BN=256, BK=64, 8 waves (2Mx4N), ring-2 x
// 64 KiB LDS k-slab regions, involution swizzle o^=((o>>3)&0x30)
// (0 conflicts), setprio, XCD swizzle.
// ---------------------------------------------------------------------------
__global__ __launch_bounds__(512, 1) void gemm_bt_kernel(
    const u16* __restrict__ A,   // [M_DIM][K]
    const u16* __restrict__ B,   // [OUT_DIM][K]
    float*     __restrict__ C) { // [M_DIM][OUT_DIM]
  constexpr int K   = IN_DIM;
  constexpr int NT  = K / 64;    // 64 K-tiles (BK=64)
  constexpr int NIT = NT / 2;    // 32 iterations (2 K-tiles each)
  extern __shared__ char smem[]; // 131072 B

  const int tid  = threadIdx.x;
  const int wave = tid >> 6;
  const int lane = tid & 63;

  // XCD-aware bijective swizzle (grid = 512, %8 == 0)
  const int swz = (blockIdx.x & 7) * 64 + (blockIdx.x >> 3);
  const int bm = (swz >> 4) * 256;   // 32 M-blocks
  const int bn = (swz & 15) * 256;   // 16 N-blocks

  const int wr  = (wave >> 2) * 128;  // 2 M-wave-groups
  const int wc  = (wave & 3) * 64;    // 4 N-wave-groups
  const int fr  = lane & 15;
  const int fkB = (lane >> 4) * 16;   // k-frag byte offset within 64B slab row

  // swizzled read offsets within a 16 KiB region (row stride 64 B)
  int offA[2][4], offB[4];
#pragma unroll
  for (int mq = 0; mq < 2; ++mq)
#pragma unroll
    for (int m = 0; m < 4; ++m) {
      int o = (wr + mq * 64 + m * 16 + fr) * 64 + fkB;
      offA[mq][m] = o ^ ((o >> 3) & 0x30);
    }
#pragma unroll
  for (int n = 0; n < 4; ++n) {
    int o = (wc + n * 16 + fr) * 64 + fkB;
    offB[n] = 16384 + (o ^ ((o >> 3) & 0x30));
  }

  // pre-swizzled global stage sources (inverse involution)
  const int d0 = tid * 16,        d1 = 8192 + tid * 16;
  const int l0 = d0 ^ ((d0 >> 3) & 0x30), l1 = d1 ^ ((d1 >> 3) & 0x30);
  const u16* srcA0 = A + (size_t)(bm + (d0 >> 6)) * K + ((l0 & 63) >> 1);
  const u16* srcA1 = A + (size_t)(bm + (d1 >> 6)) * K + ((l1 & 63) >> 1);
  const u16* srcB0 = B + (size_t)(bn + (d0 >> 6)) * K + ((l0 & 63) >> 1);
  const u16* srcB1 = B + (size_t)(bn + (d1 >> 6)) * K + ((l1 & 63) >> 1);
  const int ldsW = wave * 1024;  // wave-uniform dest base (HW adds lane*16)

#define GLD(SRC, DST)                                              \
  __builtin_amdgcn_global_load_lds(                                \
      (const __attribute__((address_space(1))) void*)(SRC),        \
      (__attribute__((address_space(3))) void*)(DST), 16, 0, 0)

  // stage one full 32 KiB k-slab region (A-part + B-part = 4 loads)
  auto stageRegion = [&](int bufi, int ks, int tile) {
    char* base = smem + bufi * 65536 + ks * 32768 + ldsW;
    const u16* a0 = srcA0 + tile * 64 + ks * 32;
    const u16* a1 = srcA1 + tile * 64 + ks * 32;
    const u16* b0 = srcB0 + tile * 64 + ks * 32;
    const u16* b1 = srcB1 + tile * 64 + ks * 32;
    GLD(a0, base);
    GLD(a1, base + 8192);
    GLD(b0, base + 16384);
    GLD(b1, base + 24576);
  };

  f32x4 acc[8][4] = {};
  bf16x8 aq0[4], aq1[4], bq0[4], bq1[4];

#define RD_A(DST, BUFI, KS, MQ)                                              \
  _Pragma("unroll")                                                          \
  for (int m = 0; m < 4; ++m)                                                \
    DST[m] = *(const bf16x8*)(smem + (BUFI) * 65536 + (KS) * 32768 +         \
                              offA[MQ][m]);
#define RD_B(DST, BUFI, KS)                                                  \
  _Pragma("unroll")                                                          \
  for (int n = 0; n < 4; ++n)                                                \
    DST[n] = *(const bf16x8*)(smem + (BUFI) * 65536 + (KS) * 32768 +         \
                              offB[n]);
#define MM(CA, CB, MQ)                                                       \
  __builtin_amdgcn_s_setprio(1);                                             \
  _Pragma("unroll")                                                          \
  for (int m = 0; m < 4; ++m)                                                \
    _Pragma("unroll")                                                        \
    for (int n = 0; n < 4; ++n)                                              \
      acc[(MQ) * 4 + m][n] = __builtin_amdgcn_mfma_f32_16x16x32_bf16(        \
          CA[m], CB[n], acc[(MQ) * 4 + m][n], 0, 0, 0);                      \
  __builtin_amdgcn_s_setprio(0);
#define BAR                                                                  \
  __builtin_amdgcn_sched_barrier(0);                                         \
  __builtin_amdgcn_s_barrier();
#define LG(N) asm volatile("s_waitcnt lgkmcnt(" #N ")" ::: "memory")
#define VM(N) asm volatile("s_waitcnt vmcnt(" #N ")" ::: "memory")

  // prologue: stage (0,0)@0,(0,1)@0,(1,0)@1 [12 loads]; retire (0,0)+(0,1)
  // (keep (1,0)); barrier; pre-read p1's frags (B(0,0), A(0,0)mq0).
  stageRegion(0, 0, 0);
  stageRegion(0, 1, 0);
  stageRegion(1, 0, 1);
  VM(4);
  __builtin_amdgcn_s_barrier();
  RD_B(bq0, 0, 0)
  RD_A(aq0, 0, 0, 0)

  for (int i = 0; i < NIT - 1; ++i) {
    const int t0 = 2 * i;
    // p1
    RD_A(aq1, 0, 0, 1)                                  BAR LG(4); MM(aq0, bq0, 0)
    // p2
    RD_B(bq1, 0, 1) RD_A(aq0, 0, 1, 0)
    stageRegion(1, 1, t0 + 1); VM(4);                   BAR LG(8); MM(aq1, bq0, 1)
    // p3
    RD_A(aq1, 0, 1, 1)                                  BAR LG(4); MM(aq0, bq1, 0)
    // p4
    RD_B(bq0, 1, 0) RD_A(aq0, 1, 0, 0)
    stageRegion(0, 0, t0 + 2); VM(4);                   BAR LG(8); MM(aq1, bq1, 1)
    // p5
    RD_A(aq1, 1, 0, 1)                                  BAR LG(4); MM(aq0, bq0, 0)
    // p6
    RD_B(bq1, 1, 1) RD_A(aq0, 1, 1, 0)
    stageRegion(0, 1, t0 + 2); VM(4);                   BAR LG(8); MM(aq1, bq0, 1)
    // p7
    RD_A(aq1, 1, 1, 1)                                  BAR LG(4); MM(aq0, bq1, 0)
    // p8
    RD_B(bq0, 0, 0) RD_A(aq0, 0, 0, 0)
    stageRegion(1, 0, t0 + 3); VM(4);                   BAR LG(8); MM(aq1, bq1, 1)
  }

  // peeled last iteration (t0 = NT-2): only (1,1)@NT-1 still staged @p2;
  // gates: VM4@p2, VM0@p4; no reads at p8.
  {
    // p1
    RD_A(aq1, 0, 0, 1)                                  BAR LG(4); MM(aq0, bq0, 0)
    // p2
    RD_B(bq1, 0, 1) RD_A(aq0, 0, 1, 0)
    stageRegion(1, 1, NT - 1); VM(4);                   BAR LG(8); MM(aq1, bq0, 1)
    // p3
    RD_A(aq1, 0, 1, 1)                                  BAR LG(4); MM(aq0, bq1, 0)
    // p4
    RD_B(bq0, 1, 0) RD_A(aq0, 1, 0, 0) VM(0);           BAR LG(8); MM(aq1, bq1, 1)
    // p5
    RD_A(aq1, 1, 0, 1)                                  BAR LG(4); MM(aq0, bq0, 0)
    // p6
    RD_B(bq1, 1, 1) RD_A(aq0, 1, 1, 0)                  BAR LG(8); MM(aq1, bq0, 1)
    // p7
    RD_A(aq1, 1, 1, 1)                                  BAR LG(4); MM(aq0, bq1, 0)
    // p8
                                                        BAR LG(0); MM(aq1, bq1, 1)
  }
#undef RD_A
#undef RD_B
#undef MM
#undef BAR
#undef LG
#undef VM
#undef GLD

  // epilogue: C/D layout col=lane&15, row=(lane>>4)*4+j (m89-verified)
#pragma unroll
  for (int h = 0; h < 8; ++h)
#pragma unroll
    for (int n = 0; n < 4; ++n) {
      const int col = bn + wc + n * 16 + fr;
#pragma unroll
      for (int j = 0; j < 4; ++j) {
        const int row = bm + wr + h * 16 + (lane >> 4) * 4 + j;
        C[(size_t)row * OUT_DIM + col] = acc[h][n][j];
      }
    }
}

// ---------------------------------------------------------------------------
extern "C" void kernel_launch(void* const* d_in, const int* in_sizes, int n_in,
                              void* d_out, int out_size, void* d_ws, size_t ws_size,
                              hipStream_t stream) {
  const float* x        = (const float*)d_in[0];
  const float* codebook = (const float*)d_in[1];
  const float* scales   = (const float*)d_in[2];
  const int*   indices  = (const int*)d_in[3];
  const int*   signs    = (const int*)d_in[4];
  float* out = (float*)d_out;

  u16* W  = (u16*)d_ws;
  u16* Xb = (u16*)d_ws + (size_t)OUT_DIM * IN_DIM;

  (void)hipFuncSetAttribute((const void*)gemm_bt_kernel,
                            hipFuncAttributeMaxDynamicSharedMemorySize, 131072);

  build_w_kernel<<<OUT_DIM, 256, 0, stream>>>(codebook, scales, indices, signs, W);
  cvt_x_kernel<<<2048, 256, 0, stream>>>(x, Xb);
  gemm_bt_kernel<<<(M_DIM / 256) * (OUT_DIM / 256), 512, 131072, stream>>>(Xb, W, out);
}

// Round 12
// 278.886 us; speedup vs baseline: 1.0499x; 1.0499x over previous
//
#include <hip/hip_runtime.h>
#include <hip/hip_bf16.h>

typedef unsigned short u16;
typedef unsigned int u32;
typedef float f32x4 __attribute__((ext_vector_type(4)));
typedef u16 u16x4 __attribute__((ext_vector_type(4)));
typedef u16 u16x8 __attribute__((ext_vector_type(8)));
typedef __bf16 bf16x8 __attribute__((ext_vector_type(8)));

#define OUT_DIM 4096
#define IN_DIM  4096
#define M_DIM   8192   // 4 * 2048

__device__ __forceinline__ u16 f2bf(float f) {
  u32 u = __builtin_bit_cast(u32, f);
  return (u16)((u + 0x7FFFu + ((u >> 16) & 1u)) >> 16);
}

// ---------------------------------------------------------------------------
// W build: codebook gather + sign unpack + 2-level inverse Haar + scale -> bf16
// ---------------------------------------------------------------------------
__global__ __launch_bounds__(256) void build_w_kernel(
    const float* __restrict__ codebook, const float* __restrict__ scales,
    const int* __restrict__ indices, const int* __restrict__ signs,
    u16* __restrict__ W) {
  __shared__ float c[IN_DIM];
  const int o   = blockIdx.x;
  const int tid = threadIdx.x;
  for (int g = tid; g < IN_DIM / 8; g += 256) {
    const int idx = indices[o * (IN_DIM / 8) + g];
    const int sp  = signs[o * (IN_DIM / 8) + g];
    f32x4 c0 = *(const f32x4*)&codebook[idx * 8];
    f32x4 c1 = *(const f32x4*)&codebook[idx * 8 + 4];
    float v[8] = {c0[0], c0[1], c0[2], c0[3], c1[0], c1[1], c1[2], c1[3]};
#pragma unroll
    for (int j = 0; j < 8; ++j)
      c[g * 8 + j] = ((sp >> j) & 1) ? v[j] : -v[j];
  }
  __syncthreads();
  const float scale = scales[o];
  const float S = 0.70710678118654752440f;
  for (int t = tid; t < IN_DIM / 4; t += 256) {
    float a   = c[t];
    float d1  = c[IN_DIM / 4 + t];
    float d2a = c[IN_DIM / 2 + 2 * t];
    float d2b = c[IN_DIM / 2 + 2 * t + 1];
    float e  = (a + d1) * S;
    float od = (a - d1) * S;
    u16x4 w;
    w[0] = f2bf((e  + d2a) * S * scale);
    w[1] = f2bf((e  - d2a) * S * scale);
    w[2] = f2bf((od + d2b) * S * scale);
    w[3] = f2bf((od - d2b) * S * scale);
    *(u16x4*)&W[(size_t)o * IN_DIM + 4 * t] = w;
  }
}

// ---------------------------------------------------------------------------
// X f32 -> bf16
// ---------------------------------------------------------------------------
__global__ __launch_bounds__(256) void cvt_x_kernel(
    const float* __restrict__ X, u16* __restrict__ Xb) {
  const int stride = gridDim.x * blockDim.x;
  const int n8 = (M_DIM * IN_DIM) / 8;
  for (int i = blockIdx.x * blockDim.x + threadIdx.x; i < n8; i += stride) {
    f32x4 a = *(const f32x4*)&X[(size_t)i * 8];
    f32x4 b = *(const f32x4*)&X[(size_t)i * 8 + 4];
    u16x8 r;
    r[0] = f2bf(a[0]); r[1] = f2bf(a[1]); r[2] = f2bf(a[2]); r[3] = f2bf(a[3]);
    r[4] = f2bf(b[0]); r[5] = f2bf(b[1]); r[6] = f2bf(b[2]); r[7] = f2bf(b[3]);
    *(u16x8*)&Xb[(size_t)i * 8] = r;
  }
}

// ---------------------------------------------------------------------------
// GEMM: C[M][N] f32 = A[M][K](bf16) x B[N][K](bf16, B^T layout).
// R12 = R10 with the two phases of each k-slab MERGED into one pair:
//   pair(p) = [read B+A0 of slab(p)] [stage slab(p+2)] [VM(4)] [s_barrier]
//             [16 MFMA mq0] [read A1] [16 MFMA mq1]
// - barriers halve (128 vs 256): no staging hazard existed between the two
//   mq-phases of one slab, so the mid-slab barrier was pure overhead.
// - A1 ds_reads drain UNDER the mq0 MFMA cluster (in-order issue gives the
//   overlap naturally; NO sched_barrier / reg-pipelining — R3/R7/R11 all
//   showed explicit order-pinning regresses on this compiler).
// - lgkm0 wall dropped: compiler emits per-use counted lgkm waits (m97).
// - barrier = asm("s_barrier":::"memory") so ds_reads cannot hoist above it.
// Hazards: RAW — slab(p) gated at pair p-1 (own VM(4)) + barrier(p-1)
//   before any read at p; prologue stages slabs 0,1 and VM(4) retires 0;
//   tail gates VM(4)/VM(4)/VM(0)/none. WAR — slab(p+2)'s last reads (pair
//   p-2) complete before that wave reaches barrier(p-1), stage@p issues
//   after barrier(p-1) release. Steady-state vmcnt never 0.
// Unchanged: 16x16x32 MFMA, BM=BN=256, BK=64 (slab=K32), 8 waves (2Mx4N),
// ring-2 x 64 KiB LDS, involution swizzle o^=((o>>3)&0x30) (0 conflicts),
// setprio around MFMA, XCD swizzle.
// ---------------------------------------------------------------------------
__global__ __launch_bounds__(512, 1) void gemm_bt_kernel(
    const u16* __restrict__ A,   // [M_DIM][K]
    const u16* __restrict__ B,   // [OUT_DIM][K]
    float*     __restrict__ C) { // [M_DIM][OUT_DIM]
  constexpr int K   = IN_DIM;
  constexpr int NT  = K / 64;    // 64 K-tiles (BK=64); 2 slabs each
  constexpr int NJ  = NT / 2;    // 32 outer iterations (4 pairs each)
  extern __shared__ char smem[]; // 131072 B

  const int tid  = threadIdx.x;
  const int wave = tid >> 6;
  const int lane = tid & 63;

  // XCD-aware bijective swizzle (grid = 512, %8 == 0)
  const int swz = (blockIdx.x & 7) * 64 + (blockIdx.x >> 3);
  const int bm = (swz >> 4) * 256;   // 32 M-blocks
  const int bn = (swz & 15) * 256;   // 16 N-blocks

  const int wr  = (wave >> 2) * 128;  // 2 M-wave-groups
  const int wc  = (wave & 3) * 64;    // 4 N-wave-groups
  const int fr  = lane & 15;
  const int fkB = (lane >> 4) * 16;   // k-frag byte offset within 64B slab row

  // swizzled read offsets within a 16 KiB region (row stride 64 B)
  int offA[2][4], offB[4];
#pragma unroll
  for (int mq = 0; mq < 2; ++mq)
#pragma unroll
    for (int m = 0; m < 4; ++m) {
      int o = (wr + mq * 64 + m * 16 + fr) * 64 + fkB;
      offA[mq][m] = o ^ ((o >> 3) & 0x30);
    }
#pragma unroll
  for (int n = 0; n < 4; ++n) {
    int o = (wc + n * 16 + fr) * 64 + fkB;
    offB[n] = 16384 + (o ^ ((o >> 3) & 0x30));
  }

  // pre-swizzled global stage sources (inverse involution)
  const int d0 = tid * 16,        d1 = 8192 + tid * 16;
  const int l0 = d0 ^ ((d0 >> 3) & 0x30), l1 = d1 ^ ((d1 >> 3) & 0x30);
  const u16* srcA0 = A + (size_t)(bm + (d0 >> 6)) * K + ((l0 & 63) >> 1);
  const u16* srcA1 = A + (size_t)(bm + (d1 >> 6)) * K + ((l1 & 63) >> 1);
  const u16* srcB0 = B + (size_t)(bn + (d0 >> 6)) * K + ((l0 & 63) >> 1);
  const u16* srcB1 = B + (size_t)(bn + (d1 >> 6)) * K + ((l1 & 63) >> 1);
  const int ldsW = wave * 1024;  // wave-uniform dest base (HW adds lane*16)

#define GLD(SRC, DST)                                              \
  __builtin_amdgcn_global_load_lds(                                \
      (const __attribute__((address_space(1))) void*)(SRC),        \
      (__attribute__((address_space(3))) void*)(DST), 16, 0, 0)

  // stage one full 32 KiB k-slab region (A-part + B-part = 4 loads)
  auto stageRegion = [&](int bufi, int ks, int tile) {
    char* base = smem + bufi * 65536 + ks * 32768 + ldsW;
    const u16* a0 = srcA0 + tile * 64 + ks * 32;
    const u16* a1 = srcA1 + tile * 64 + ks * 32;
    const u16* b0 = srcB0 + tile * 64 + ks * 32;
    const u16* b1 = srcB1 + tile * 64 + ks * 32;
    GLD(a0, base);
    GLD(a1, base + 8192);
    GLD(b0, base + 16384);
    GLD(b1, base + 24576);
  };

  f32x4 acc[8][4] = {};
  bf16x8 aqA[4], aqB[4], bq[4];

#define VM4 asm volatile("s_waitcnt vmcnt(4)" ::: "memory")
#define VM0 asm volatile("s_waitcnt vmcnt(0)" ::: "memory")
#define BARM asm volatile("s_barrier" ::: "memory")

  // pair: read B+A0(slab); stage; gate; barrier; MFMA mq0; read A1; MFMA mq1
#define PAIR(BUFI, KS, STG, GATE)                                            \
  {                                                                          \
    const char* rb = smem + (BUFI) * 65536 + (KS) * 32768;                   \
    _Pragma("unroll")                                                        \
    for (int n = 0; n < 4; ++n) bq[n] = *(const bf16x8*)(rb + offB[n]);      \
    _Pragma("unroll")                                                        \
    for (int m = 0; m < 4; ++m) aqA[m] = *(const bf16x8*)(rb + offA[0][m]);  \
    STG;                                                                     \
    GATE;                                                                    \
    BARM;                                                                    \
    __builtin_amdgcn_s_setprio(1);                                           \
    _Pragma("unroll")                                                        \
    for (int m = 0; m < 4; ++m)                                              \
      _Pragma("unroll")                                                      \
      for (int n = 0; n < 4; ++n)                                            \
        acc[m][n] = __builtin_amdgcn_mfma_f32_16x16x32_bf16(                 \
            aqA[m], bq[n], acc[m][n], 0, 0, 0);                              \
    __builtin_amdgcn_s_setprio(0);                                           \
    _Pragma("unroll")                                                        \
    for (int m = 0; m < 4; ++m) aqB[m] = *(const bf16x8*)(rb + offA[1][m]);  \
    __builtin_amdgcn_s_setprio(1);                                           \
    _Pragma("unroll")                                                        \
    for (int m = 0; m < 4; ++m)                                              \
      _Pragma("unroll")                                                      \
      for (int n = 0; n < 4; ++n)                                            \
        acc[4 + m][n] = __builtin_amdgcn_mfma_f32_16x16x32_bf16(             \
            aqB[m], bq[n], acc[4 + m][n], 0, 0, 0);                          \
    __builtin_amdgcn_s_setprio(0);                                           \
  }

  // prologue: stage slab0 (buf0,ks0,t0) and slab1 (buf0,ks1,t0) = 8 loads;
  // VM(4) retires slab0 (slab1 stays in flight); barrier.
  stageRegion(0, 0, 0);
  stageRegion(0, 1, 0);
  VM4;
  BARM;

  for (int j = 0; j < NJ - 1; ++j) {
    const int t0 = 2 * j;
    // pairs 4j..4j+3: slabs (0,0)(0,1)(1,0)(1,1) of tiles t0, t0+1
    PAIR(0, 0, stageRegion(1, 0, t0 + 1), VM4)
    PAIR(0, 1, stageRegion(1, 1, t0 + 1), VM4)
    PAIR(1, 0, stageRegion(0, 0, t0 + 2), VM4)
    PAIR(1, 1, stageRegion(0, 1, t0 + 2), VM4)
  }

  // peeled last outer iteration (tiles NT-2, NT-1):
  // p124 stages (1,0)@NT-1, p125 stages (1,1)@NT-1, p126 gates VM0, p127 free.
  PAIR(0, 0, stageRegion(1, 0, NT - 1), VM4)
  PAIR(0, 1, stageRegion(1, 1, NT - 1), VM4)
  PAIR(1, 0, , VM0)
  PAIR(1, 1, , )
#undef PAIR
#undef GLD
#undef VM4
#undef VM0
#undef BARM

  // epilogue: C/D layout col=lane&15, row=(lane>>4)*4+j (m89-verified)
#pragma unroll
  for (int h = 0; h < 8; ++h)
#pragma unroll
    for (int n = 0; n < 4; ++n) {
      const int col = bn + wc + n * 16 + fr;
#pragma unroll
      for (int j = 0; j < 4; ++j) {
        const int row = bm + wr + h * 16 + (lane >> 4) * 4 + j;
        C[(size_t)row * OUT_DIM + col] = acc[h][n][j];
      }
    }
}

// ---------------------------------------------------------------------------
extern "C" void kernel_launch(void* const* d_in, const int* in_sizes, int n_in,
                              void* d_out, int out_size, void* d_ws, size_t ws_size,
                              hipStream_t stream) {
  const float* x        = (const float*)d_in[0];
  const float* codebook = (const float*)d_in[1];
  const float* scales   = (const float*)d_in[2];
  const int*   indices  = (const int*)d_in[3];
  const int*   signs    = (const int*)d_in[4];
  float* out = (float*)d_out;

  u16* W  = (u16*)d_ws;
  u16* Xb = (u16*)d_ws + (size_t)OUT_DIM * IN_DIM;

  (void)hipFuncSetAttribute((const void*)gemm_bt_kernel,
                            hipFuncAttributeMaxDynamicSharedMemorySize, 131072);

  build_w_kernel<<<OUT_DIM, 256, 0, stream>>>(codebook, scales, indices, signs, W);
  cvt_x_kernel<<<2048, 256, 0, stream>>>(x, Xb);
  gemm_bt_kernel<<<(M_DIM / 256) * (OUT_DIM / 256), 512, 131072, stream>>>(Xb, W, out);
}